// Round 4
// baseline (43.848 us; speedup 1.0000x reference)
//
#include <hip/hip_runtime.h>

// ClustCNNEdgeEncoder: for each edge e=(a,b), gather data[clusts[a]] ++ data[clusts[b]]
// (5 cols), overwrite col 3 with (float)e. Output [E*2P, 5] f32, row-major.
// E=40000, P=100 -> per-edge slab = 1000 floats (4000 B, 16B-aligned).
//
// Phase 1: compact data[clusts[:]] -> d_ws [N_CLUSTS*500] f32 (4 MB, L2/L3-resident).
// Phase 2: 4 edges per block; each thread handles ~4 independent float4 copy+stamp
//          pairs for ILP; nontemporal stores keep the 156 MB write stream out of L2.

#define NPTS_PER_CLUST 100
#define EDGES_PER_BLOCK 4

typedef float f32x4 __attribute__((ext_vector_type(4)));

// Phase 1: compact[c*500 + j*5 + col] = data[clusts[c*100+j]*5 + col]
__global__ __launch_bounds__(256) void compact_kernel(
    const float* __restrict__ data,     // [N_POINTS, 5]
    const int*   __restrict__ clusts,   // [N_CLUSTS * 100] flat
    float*       __restrict__ compact,  // [N_CLUSTS * 500]
    int total)                          // N_CLUSTS * 500
{
    int tid = blockIdx.x * blockDim.x + threadIdx.x;
    if (tid < total) {
        int row = tid / 5;
        int col = tid - row * 5;
        int p   = clusts[row];
        compact[tid] = data[p * 5 + col];
    }
}

// Phase 2: block b handles edges [b*4, b*4+4); 1000 float4s per block over 256 threads.
__global__ __launch_bounds__(256) void edge_copy_kernel(
    const int*   __restrict__ edge_index,  // [2, E]
    const float* __restrict__ compact,     // [N_CLUSTS * 500]
    float*       __restrict__ out,         // [E * 1000]
    int E)
{
    __shared__ int sh_cl[2 * EDGES_PER_BLOCK];   // [edge_loc][half]

    const int b = blockIdx.x;
    const int t = threadIdx.x;
    const int e0 = b * EDGES_PER_BLOCK;
    const int n_e = min(EDGES_PER_BLOCK, E - e0);
    const int n_f4 = n_e * 250;

    if (t < 2 * EDGES_PER_BLOCK) {
        const int el   = t >> 1;
        const int half = t & 1;
        sh_cl[t] = (el < n_e) ? edge_index[half * E + (e0 + el)] : 0;
    }
    __syncthreads();

    f32x4 v[4];
    int   ki[4];
    int   el_a[4];

#pragma unroll
    for (int k = 0; k < 4; ++k) {
        const int i = t + k * 256;               // f4 index within block slab [0,1000)
        if (i < n_f4) {
            const int el   = i / 250;            // local edge
            const int q    = i - el * 250;       // f4 within edge slab
            const int half = (q >= 125);
            const int qq   = q - half * 125;
            const int cl   = sh_cl[el * 2 + half];
            v[k] = reinterpret_cast<const f32x4*>(compact + (size_t)cl * 500)[qq];
            const int m = (q * 4) % 5;
            ki[k]   = (3 - m + 5) % 5;           // element to stamp; 4 = none
            el_a[k] = el;
        }
    }

#pragma unroll
    for (int k = 0; k < 4; ++k) {
        const int i = t + k * 256;
        if (i < n_f4) {
            const float ef = (float)(e0 + el_a[k]);
            const int kk = ki[k];
            if      (kk == 0) v[k].x = ef;
            else if (kk == 1) v[k].y = ef;
            else if (kk == 2) v[k].z = ef;
            else if (kk == 3) v[k].w = ef;
            __builtin_nontemporal_store(v[k],
                reinterpret_cast<f32x4*>(out + (size_t)b * (EDGES_PER_BLOCK * 1000)) + i);
        }
    }
}

// Fallback (ws too small): direct gather (R1 kernel).
__global__ __launch_bounds__(256) void direct_kernel(
    const float* __restrict__ data,
    const int*   __restrict__ clusts,
    const int*   __restrict__ edge_index,
    float*       __restrict__ out,
    int E)
{
    __shared__ int sh_pts[2 * NPTS_PER_CLUST];
    const int e = blockIdx.x;
    const int t = threadIdx.x;
    if (t < 2 * NPTS_PER_CLUST) {
        const int cl  = (t < NPTS_PER_CLUST) ? edge_index[e] : edge_index[E + e];
        const int off = (t < NPTS_PER_CLUST) ? t : t - NPTS_PER_CLUST;
        sh_pts[t] = clusts[cl * NPTS_PER_CLUST + off];
    }
    __syncthreads();
    if (t < 250) {
        const float edge_f = (float)e;
        float vals[4];
#pragma unroll
        for (int kk = 0; kk < 4; ++kk) {
            const int el = t * 4 + kk;
            const int r  = el / 5;
            const int c  = el - r * 5;
            vals[kk] = (c == 3) ? edge_f : data[sh_pts[r] * 5 + c];
        }
        float4 v; v.x = vals[0]; v.y = vals[1]; v.z = vals[2]; v.w = vals[3];
        reinterpret_cast<float4*>(out + (size_t)e * 1000)[t] = v;
    }
}

extern "C" void kernel_launch(void* const* d_in, const int* in_sizes, int n_in,
                              void* d_out, int out_size, void* d_ws, size_t ws_size,
                              hipStream_t stream) {
    const float* data       = (const float*)d_in[0];
    const int*   clusts     = (const int*)d_in[1];
    const int*   edge_index = (const int*)d_in[2];
    float*       out        = (float*)d_out;

    const int E        = in_sizes[2] / 2;          // edge_index is [2, E]
    const int n_clpts  = in_sizes[1];              // N_CLUSTS * 100
    const int total    = n_clpts * 5;              // compact element count
    const size_t need  = (size_t)total * sizeof(float);

    if (ws_size >= need) {
        float* compact = (float*)d_ws;
        compact_kernel<<<(total + 255) / 256, 256, 0, stream>>>(data, clusts, compact, total);
        const int nblk = (E + EDGES_PER_BLOCK - 1) / EDGES_PER_BLOCK;
        edge_copy_kernel<<<nblk, 256, 0, stream>>>(edge_index, compact, out, E);
    } else {
        direct_kernel<<<E, 256, 0, stream>>>(data, clusts, edge_index, out, E);
    }
}